// Round 1
// baseline (2324.930 us; speedup 1.0000x reference)
//
#include <hip/hip_runtime.h>
#include <math.h>

#define HW 1024

__device__ __forceinline__ float elu_f(float x) { return x > 0.f ? x : (__expf(x) - 1.f); }
__device__ __forceinline__ float sig_f(float x) { return 1.f / (1.f + __expf(-x)); }

enum { IM_PLAIN, IM_ELU, IM_ELU_SUM, IM_IM2COL_ELU, IM_PIXMAJOR };
enum { OM_PLAIN, OM_ELU, OM_ELU_RES, OM_QKV };

// Generic tiled GEMM: out[b][m][p] = epilogue( sum_k Aw[m][k] * B(b,k,p) + bias[m] )
// BM=BN=64, BK=32, 256 threads, 4x4 micro-tile per thread.
// B(b,k,p) is built on the fly per IM mode (plain / elu / elu(sum) / im2col+elu / pixel-major).
template<int IM, int OM>
__global__ __launch_bounds__(256)
void gemm_k(const float* __restrict__ Aw, const float* __restrict__ bias,
            const float* __restrict__ in0, const float* __restrict__ in1,
            float* __restrict__ out0, float* __restrict__ out1, float* __restrict__ out2,
            const float* __restrict__ res, int M, int K, int wstride)
{
    __shared__ float As[32][68];   // [k][m], pad 68 keeps float4 alignment (68*4B=272=17*16)
    __shared__ float Bs[32][68];   // [k][n]
    const int tid = threadIdx.x;
    const int b  = blockIdx.z;
    const int p0 = blockIdx.x * 64;
    const int m0 = blockIdx.y * 64;
    const int tx = tid & 15, ty = tid >> 4;
    float acc[4][4] = {};
    const float* inb = in0 + (size_t)b * 131072;   // all activation inputs are (B,*,*) with 131072 f/batch

    for (int k0 = 0; k0 < K; k0 += 32) {
        // ---- stage A (weights, row-major (M, wstride)) ----
        {
            const int m  = tid >> 2;
            const int kb = (tid & 3) * 8;
            const bool mok = (m0 + m) < M;
            const float* wrow = Aw + (size_t)(m0 + m) * wstride + k0 + kb;
            #pragma unroll
            for (int j = 0; j < 8; ++j)
                As[kb + j][m] = mok ? wrow[j] : 0.f;
        }
        // ---- stage B ----
        if constexpr (IM == IM_PLAIN || IM == IM_ELU || IM == IM_ELU_SUM) {
            const int k = tid >> 3;
            const int n = (tid & 7) * 8;
            const float* src = inb + (size_t)(k0 + k) * HW + p0 + n;
            float vv[8];
            *(float4*)(vv)     = *(const float4*)(src);
            *(float4*)(vv + 4) = *(const float4*)(src + 4);
            if constexpr (IM == IM_ELU_SUM) {
                const float* src1 = in1 + (size_t)b * 131072 + (size_t)(k0 + k) * HW + p0 + n;
                float w2[8];
                *(float4*)(w2)     = *(const float4*)(src1);
                *(float4*)(w2 + 4) = *(const float4*)(src1 + 4);
                #pragma unroll
                for (int j = 0; j < 8; ++j) vv[j] += w2[j];
            }
            #pragma unroll
            for (int j = 0; j < 8; ++j)
                Bs[k][n + j] = (IM == IM_PLAIN) ? vv[j] : elu_f(vv[j]);
        } else if constexpr (IM == IM_IM2COL_ELU) {
            // k = c*4 + tap, tap=(ky,kx) in {0,1}^2, input pixel offset (ky-1)*32+(kx-1)
            const int kk  = tid >> 3;
            const int nb  = (tid & 7) * 8;
            const int kfull = k0 + kk;
            const int c   = kfull >> 2;
            const int tap = kfull & 3;
            const int ky = tap >> 1, kx = tap & 1;
            const int off = (ky - 1) * 32 + (kx - 1);
            const float* srcc = inb + (size_t)c * HW;
            #pragma unroll
            for (int j = 0; j < 8; ++j) {
                const int p = p0 + nb + j;
                const int y = p >> 5, xp = p & 31;
                const bool ok = (ky == 1 || y > 0) && (kx == 1 || xp > 0);
                Bs[kk][nb + j] = ok ? elu_f(srcc[p + off]) : 0.f;
            }
        } else { // IM_PIXMAJOR: in0 is (B, HW, 128)
            #pragma unroll
            for (int half = 0; half < 2; ++half) {
                const int n = (tid >> 3) + half * 32;
                const int k = (tid & 7) * 4;
                const float4 v4 = *(const float4*)(inb + (size_t)(p0 + n) * 128 + k0 + k);
                Bs[k][n] = v4.x; Bs[k+1][n] = v4.y; Bs[k+2][n] = v4.z; Bs[k+3][n] = v4.w;
            }
        }
        __syncthreads();
        #pragma unroll
        for (int kk = 0; kk < 32; ++kk) {
            const float4 a4 = *(const float4*)&As[kk][ty * 4];
            const float4 b4 = *(const float4*)&Bs[kk][tx * 4];
            const float av[4]  = {a4.x, a4.y, a4.z, a4.w};
            const float bvv[4] = {b4.x, b4.y, b4.z, b4.w};
            #pragma unroll
            for (int mi = 0; mi < 4; ++mi)
                #pragma unroll
                for (int ni = 0; ni < 4; ++ni)
                    acc[mi][ni] = fmaf(av[mi], bvv[ni], acc[mi][ni]);
        }
        __syncthreads();
    }
    // ---- epilogue ----
    #pragma unroll
    for (int mi = 0; mi < 4; ++mi) {
        const int m = m0 + ty * 4 + mi;
        if (m >= M) continue;
        const float bv = bias[m];
        if constexpr (OM == OM_QKV) {
            // add positional-encoding columns 128 (py) and 129 (px), split q/k/v transposed
            const float wy = Aw[(size_t)m * wstride + 128];
            const float wx = Aw[(size_t)m * wstride + 129];
            #pragma unroll
            for (int ni = 0; ni < 4; ++ni) {
                const int p = p0 + tx * 4 + ni;
                const float py = (float)(p >> 5) * 0.03125f - 0.5f;
                const float px = (float)(p & 31) * 0.03125f - 0.5f;
                const float v = acc[mi][ni] + bv + wy * py + wx * px;
                if (m < 16)      out0[((size_t)b * HW + p) * 16 + m] = v;
                else if (m < 32) out1[((size_t)b * HW + p) * 16 + (m - 16)] = v;
                else             out2[((size_t)b * HW + p) * 128 + (m - 32)] = v;
            }
        } else {
            const int p = p0 + tx * 4;
            float vv[4];
            #pragma unroll
            for (int ni = 0; ni < 4; ++ni) vv[ni] = acc[mi][ni] + bv;
            if constexpr (OM == OM_ELU) {
                #pragma unroll
                for (int ni = 0; ni < 4; ++ni) vv[ni] = elu_f(vv[ni]);
            } else if constexpr (OM == OM_ELU_RES) {
                const float4 r4 = *(const float4*)&res[((size_t)b * 128 + m) * HW + p];
                vv[0] = elu_f(vv[0]) + r4.x; vv[1] = elu_f(vv[1]) + r4.y;
                vv[2] = elu_f(vv[2]) + r4.z; vv[3] = elu_f(vv[3]) + r4.w;
            }
            float4 ov; ov.x = vv[0]; ov.y = vv[1]; ov.z = vv[2]; ov.w = vv[3];
            *(float4*)&out0[((size_t)b * M + m) * HW + p] = ov;
        }
    }
}

// out = prev + t1 * sigmoid(t2), t = (B,256,HW) with t1=ch[0:128), t2=ch[128:256)
__global__ __launch_bounds__(256)
void gate_k(const float* __restrict__ prev, const float* __restrict__ t, float* __restrict__ outp)
{
    const size_t i4 = ((size_t)blockIdx.x * 256 + threadIdx.x) * 4;
    const size_t b = i4 >> 17;          // 131072 floats per batch
    const size_t r = i4 & 131071;
    const float4 pv = *(const float4*)(prev + i4);
    const float4 t1 = *(const float4*)(t + b * 262144 + r);
    const float4 t2 = *(const float4*)(t + b * 262144 + 131072 + r);
    float4 o;
    o.x = pv.x + t1.x * sig_f(t2.x);
    o.y = pv.y + t1.y * sig_f(t2.y);
    o.z = pv.z + t1.z * sig_f(t2.z);
    o.w = pv.w + t1.w * sig_f(t2.w);
    *(float4*)(outp + i4) = o;
}

// Causal flash attention: q,k (B,HW,16), v,o (B,HW,128). scale=0.25, one head.
// Block: 32 queries, 256 threads (thread = (row, d-group of 16)), 64-key chunks, online softmax.
__global__ __launch_bounds__(256)
void attn_k(const float* __restrict__ q, const float* __restrict__ k,
            const float* __restrict__ v, float* __restrict__ o)
{
    __shared__ float qs[32][17];   // pad 17: avoids 32-way bank conflict on column reads
    __shared__ float ks[64][16];
    __shared__ float ss[32][65];   // pad 65: row stride coprime with 32 banks
    const int tid = threadIdx.x;
    const int b  = blockIdx.y;
    const int q0 = blockIdx.x * 32;
    for (int e = tid; e < 512; e += 256)
        qs[e >> 4][e & 15] = q[((size_t)b * HW + q0 + (e >> 4)) * 16 + (e & 15)];
    const int irow = tid >> 3, dg = tid & 7;
    const int si = tid & 31,  sj0 = tid >> 5;
    float acc[16] = {};
    float mrun = -INFINITY, lrun = 0.f;
    const int nk = q0 + 32;
    for (int j0 = 0; j0 < nk; j0 += 64) {
        __syncthreads();   // qs ready (iter 0) / previous PV done with ss,ks
        {
            const int e = tid * 4;
            const int j = e >> 4, d = e & 15;
            *(float4*)&ks[j][d] = *(const float4*)(k + ((size_t)b * HW + j0 + j) * 16 + d);
        }
        __syncthreads();
        const int jn = (nk - j0 < 64) ? (nk - j0) : 64;
        #pragma unroll
        for (int t8 = 0; t8 < 8; ++t8) {
            const int jj = sj0 * 8 + t8;
            float dot = 0.f;
            #pragma unroll
            for (int d = 0; d < 16; ++d) dot = fmaf(qs[si][d], ks[jj][d], dot);
            ss[si][jj] = (jj < jn && (j0 + jj) <= (q0 + si)) ? dot * 0.25f : -INFINITY;
        }
        __syncthreads();
        float mc = mrun;
        #pragma unroll 8
        for (int jj = 0; jj < 64; ++jj) mc = fmaxf(mc, ss[irow][jj]);
        if (mc > -INFINITY) {  // row has at least one valid key in this chunk
            const float corr = __expf(mrun - mc);   // mrun=-inf -> 0
            lrun *= corr;
            #pragma unroll
            for (int d = 0; d < 16; ++d) acc[d] *= corr;
            const float* vbase = v + ((size_t)b * HW + j0) * 128 + dg * 16;
            for (int jj = 0; jj < 64; ++jj) {
                const float pexp = __expf(ss[irow][jj] - mc);  // masked -> exp(-inf)=0
                lrun += pexp;
                const float* vrow = vbase + (size_t)jj * 128;
                #pragma unroll
                for (int d4 = 0; d4 < 4; ++d4) {
                    const float4 vv = *(const float4*)(vrow + d4 * 4);
                    acc[d4*4+0] = fmaf(pexp, vv.x, acc[d4*4+0]);
                    acc[d4*4+1] = fmaf(pexp, vv.y, acc[d4*4+1]);
                    acc[d4*4+2] = fmaf(pexp, vv.z, acc[d4*4+2]);
                    acc[d4*4+3] = fmaf(pexp, vv.w, acc[d4*4+3]);
                }
            }
            mrun = mc;
        }
    }
    const float inv = 1.f / lrun;
    float* orow = o + ((size_t)b * HW + q0 + irow) * 128 + dg * 16;
    #pragma unroll
    for (int d4 = 0; d4 < 4; ++d4) {
        float4 ov;
        ov.x = acc[d4*4+0] * inv; ov.y = acc[d4*4+1] * inv;
        ov.z = acc[d4*4+2] * inv; ov.w = acc[d4*4+3] * inv;
        *(float4*)(orow + d4 * 4) = ov;
    }
}

extern "C" void kernel_launch(void* const* d_in, const int* in_sizes, int n_in,
                              void* d_out, int out_size, void* d_ws, size_t ws_size,
                              hipStream_t stream) {
    const float* x    = (const float*)d_in[0];
    const float* rw1  = (const float*)d_in[1];
    const float* rb1  = (const float*)d_in[2];
    const float* rw2  = (const float*)d_in[3];
    const float* rb2  = (const float*)d_in[4];
    const float* qkvw = (const float*)d_in[5];
    const float* qkvb = (const float*)d_in[6];
    const float* apw  = (const float*)d_in[7];
    const float* apb  = (const float*)d_in[8];
    const float* ocw  = (const float*)d_in[9];
    const float* ocb  = (const float*)d_in[10];
    const float* oaw  = (const float*)d_in[11];
    const float* oab  = (const float*)d_in[12];
    const float* opw  = (const float*)d_in[13];
    const float* opb  = (const float*)d_in[14];
    float* out = (float*)d_out;
    float* ws = (float*)d_ws;

    // Workspace regions (floats). Total = 16,777,216 f = 64 MiB.
    float* A = ws;                       // (B,128,HW) residual-stack activations
    float* C = ws + 4194304;             // (B,128,HW) t / o / c1
    float* D = ws + 8388608;             // (B,256,HW) t2 / {q,k,v} / attn_out+a1
    float* qb = D;                       // (B,HW,16)
    float* kb = D + 524288;              // (B,HW,16)
    float* vb = D + 1048576;             // (B,HW,128)
    float* ob = C;                       // (B,HW,128)
    float* attnout = D;                  // (B,128,HW)
    float* c1 = C;                       // (B,128,HW)
    float* a1 = D + 4194304;             // (B,128,HW)

    dim3 blk(256);
    for (int i = 0; i < 6; ++i) {
        const float* prev = i ? (const float*)A : x;
        gemm_k<IM_IM2COL_ELU, OM_PLAIN><<<dim3(16, 2, 32), blk, 0, stream>>>(
            rw1 + (size_t)i * 65536, rb1 + i * 128, prev, nullptr,
            C, nullptr, nullptr, nullptr, 128, 512, 512);
        gemm_k<IM_IM2COL_ELU, OM_PLAIN><<<dim3(16, 4, 32), blk, 0, stream>>>(
            rw2 + (size_t)i * 131072, rb2 + i * 256, C, nullptr,
            D, nullptr, nullptr, nullptr, 256, 512, 512);
        gate_k<<<4096, blk, 0, stream>>>(prev, D, A);
    }
    // qkv (M=160, K=128 GEMM + analytic pos-enc columns), conv input NOT elu'd
    gemm_k<IM_PLAIN, OM_QKV><<<dim3(16, 3, 32), blk, 0, stream>>>(
        qkvw, qkvb, A, nullptr, qb, kb, vb, nullptr, 160, 128, 130);
    // causal attention
    attn_k<<<dim3(32, 32), blk, 0, stream>>>(qb, kb, vb, ob);
    // attn_proj: pixel-major input o -> channel-major attn_out
    gemm_k<IM_PIXMAJOR, OM_PLAIN><<<dim3(16, 2, 32), blk, 0, stream>>>(
        apw, apb, ob, nullptr, attnout, nullptr, nullptr, nullptr, 128, 128, 128);
    // c1 = elu(W * elu(conv) + b)
    gemm_k<IM_ELU, OM_ELU><<<dim3(16, 2, 32), blk, 0, stream>>>(
        ocw, ocb, A, nullptr, c1, nullptr, nullptr, nullptr, 128, 128, 128);
    // a1 = elu(W * elu(attn_out) + b)
    gemm_k<IM_ELU, OM_ELU><<<dim3(16, 2, 32), blk, 0, stream>>>(
        oaw, oab, attnout, nullptr, a1, nullptr, nullptr, nullptr, 128, 128, 128);
    // y = elu(W * elu(c1 + a1) + b) + x
    gemm_k<IM_ELU_SUM, OM_ELU_RES><<<dim3(16, 2, 32), blk, 0, stream>>>(
        opw, opb, c1, a1, out, nullptr, nullptr, x, 128, 128, 128);
}

// Round 2
// 1009.610 us; speedup vs baseline: 2.3028x; 2.3028x over previous
//
#include <hip/hip_runtime.h>
#include <math.h>

#define HW 1024

typedef __attribute__((ext_vector_type(8))) short short8v;   // 8 bf16 (4 VGPRs)
typedef __attribute__((ext_vector_type(4))) float f32x4;

__device__ __forceinline__ float elu_f(float x) { return x > 0.f ? x : (__expf(x) - 1.f); }
__device__ __forceinline__ float sig_f(float x) { return 1.f / (1.f + __expf(-x)); }
__device__ __forceinline__ unsigned short f2bf(float f) {
    unsigned int u = __float_as_uint(f);
    return (unsigned short)((u + 0x7fffu + ((u >> 16) & 1u)) >> 16);   // RNE
}

// 16B-granule XOR swizzle for [row][32 bf16] LDS tiles: 8 distinct granules per 8 rows.
#define SW(r) ((((r) >> 1) & 3) << 4)

// ---------------------------------------------------------------------------
// bf16 MFMA conv2x2 (im2col GEMM): out[b, p, n] = sum_k im2col(b,p,k) * W[n][k]
// D rows = pixels (A operand = im2col), D cols = out-channels (B operand = W).
// Block: 64 pixels x NOUT channels, K=512, BK=32, 256 threads = 4 waves.
// A-frag lane l: A[p = l&15][k = (l>>4)*8+j]; B-frag lane l: B[k=(l>>4)*8+j][n=l&15];
// D lane l: rows (l>>4)*4+r (pixels), col l&15 (channel).
// ---------------------------------------------------------------------------
template<int NOUT, bool ELU_BF16_OUT>
__global__ __launch_bounds__(256)
void conv_mfma(const unsigned short* __restrict__ Ein, const float* __restrict__ W,
               const float* __restrict__ bias, void* __restrict__ outp)
{
    constexpr int NF = NOUT / 32;               // n-frags per wave (wave covers NOUT/2 channels)
    __shared__ unsigned short As[64 * 32];      // swizzled [pix][k]
    __shared__ unsigned short Ws[NOUT * 32];    // swizzled [ch][k]
    const int tid = threadIdx.x;
    const int b  = blockIdx.z;
    const int p0 = blockIdx.x * 64;
    const int wv = tid >> 6, lane = tid & 63;
    const int pw = (wv & 1) * 32, cw = (wv >> 1) * (NOUT / 2);
    const int lr = lane & 15, lg = lane >> 4;
    const unsigned short* Eb = Ein + (size_t)b * 131072;
    f32x4 acc[2][NF] = {};

    const int ar = tid >> 2, akb = (tid & 3) * 8;   // A-stage: row, k-granule base
    const int ap = p0 + ar, ay = ap >> 5, ax = ap & 31;

    for (int k0 = 0; k0 < 512; k0 += 32) {
        __syncthreads();
        // ---- stage A: im2col gather from bf16 activations ----
        {
            short8v av;
            #pragma unroll
            for (int j = 0; j < 8; ++j) {
                const int kk = k0 + akb + j;
                const int c = kk >> 2, tap = kk & 3;
                const int ky = tap >> 1, kx = tap & 1;
                const bool ok = (ky == 1 || ay > 0) && (kx == 1 || ax > 0);
                av[j] = ok ? (short)Eb[c * HW + ap + (ky - 1) * 32 + (kx - 1)] : (short)0;
            }
            *(short8v*)((char*)As + ar * 64 + (((akb >> 3) << 4) ^ SW(ar))) = av;
        }
        // ---- stage W: f32 -> bf16 ----
        for (int n = tid; n < NOUT; n += 256) {
            const float* wr = W + (size_t)n * 512 + k0;
            #pragma unroll
            for (int g = 0; g < 4; ++g) {
                const float4 wa = *(const float4*)(wr + g * 8);
                const float4 wb = *(const float4*)(wr + g * 8 + 4);
                short8v wv8;
                wv8[0] = (short)f2bf(wa.x); wv8[1] = (short)f2bf(wa.y);
                wv8[2] = (short)f2bf(wa.z); wv8[3] = (short)f2bf(wa.w);
                wv8[4] = (short)f2bf(wb.x); wv8[5] = (short)f2bf(wb.y);
                wv8[6] = (short)f2bf(wb.z); wv8[7] = (short)f2bf(wb.w);
                *(short8v*)((char*)Ws + n * 64 + ((g << 4) ^ SW(n))) = wv8;
            }
        }
        __syncthreads();
        // ---- fragments + MFMA ----
        short8v af[2];
        #pragma unroll
        for (int pf = 0; pf < 2; ++pf) {
            const int row = pw + pf * 16 + lr;
            af[pf] = *(const short8v*)((char*)As + row * 64 + ((lg << 4) ^ SW(row)));
        }
        #pragma unroll
        for (int nf = 0; nf < NF; ++nf) {
            const int n = cw + nf * 16 + lr;
            const short8v bfg = *(const short8v*)((char*)Ws + n * 64 + ((lg << 4) ^ SW(n)));
            acc[0][nf] = __builtin_amdgcn_mfma_f32_16x16x32_bf16(af[0], bfg, acc[0][nf], 0, 0, 0);
            acc[1][nf] = __builtin_amdgcn_mfma_f32_16x16x32_bf16(af[1], bfg, acc[1][nf], 0, 0, 0);
        }
    }
    // ---- epilogue ----
    #pragma unroll
    for (int pf = 0; pf < 2; ++pf) {
        #pragma unroll
        for (int nf = 0; nf < NF; ++nf) {
            const int n = cw + nf * 16 + lr;
            const float bv = bias[n];
            const int pl = p0 + pw + pf * 16 + lg * 4;   // 4 consecutive pixels
            if constexpr (ELU_BF16_OUT) {
                ushort4 e4;
                e4.x = f2bf(elu_f(acc[pf][nf][0] + bv));
                e4.y = f2bf(elu_f(acc[pf][nf][1] + bv));
                e4.z = f2bf(elu_f(acc[pf][nf][2] + bv));
                e4.w = f2bf(elu_f(acc[pf][nf][3] + bv));
                *(ushort4*)((unsigned short*)outp + (size_t)b * 131072 + n * HW + pl) = e4;
            } else {
                float4 o4;
                o4.x = acc[pf][nf][0] + bv; o4.y = acc[pf][nf][1] + bv;
                o4.z = acc[pf][nf][2] + bv; o4.w = acc[pf][nf][3] + bv;
                *(float4*)((float*)outp + ((size_t)b * NOUT + n) * HW + pl) = o4;
            }
        }
    }
}

// ---------------------------------------------------------------------------
// fp32 tiled GEMM for head layers (unchanged core from round 1).
// ---------------------------------------------------------------------------
enum { IM_PLAIN, IM_ELU, IM_ELU_SUM, IM_PIXMAJOR };
enum { OM_PLAIN, OM_ELU, OM_ELU_RES, OM_QKV };

template<int IM, int OM>
__global__ __launch_bounds__(256)
void gemm_k(const float* __restrict__ Aw, const float* __restrict__ bias,
            const float* __restrict__ in0, const float* __restrict__ in1,
            float* __restrict__ out0, float* __restrict__ out1, float* __restrict__ out2,
            const float* __restrict__ res, int M, int K, int wstride)
{
    __shared__ float As[32][68];
    __shared__ float Bs[32][68];
    const int tid = threadIdx.x;
    const int b  = blockIdx.z;
    const int p0 = blockIdx.x * 64;
    const int m0 = blockIdx.y * 64;
    const int tx = tid & 15, ty = tid >> 4;
    float acc[4][4] = {};
    const float* inb = in0 + (size_t)b * 131072;

    for (int k0 = 0; k0 < K; k0 += 32) {
        {
            const int m  = tid >> 2;
            const int kb = (tid & 3) * 8;
            const bool mok = (m0 + m) < M;
            const float* wrow = Aw + (size_t)(m0 + m) * wstride + k0 + kb;
            #pragma unroll
            for (int j = 0; j < 8; ++j)
                As[kb + j][m] = mok ? wrow[j] : 0.f;
        }
        if constexpr (IM == IM_PLAIN || IM == IM_ELU || IM == IM_ELU_SUM) {
            const int k = tid >> 3;
            const int n = (tid & 7) * 8;
            const float* src = inb + (size_t)(k0 + k) * HW + p0 + n;
            float vv[8];
            *(float4*)(vv)     = *(const float4*)(src);
            *(float4*)(vv + 4) = *(const float4*)(src + 4);
            if constexpr (IM == IM_ELU_SUM) {
                const float* src1 = in1 + (size_t)b * 131072 + (size_t)(k0 + k) * HW + p0 + n;
                float w2[8];
                *(float4*)(w2)     = *(const float4*)(src1);
                *(float4*)(w2 + 4) = *(const float4*)(src1 + 4);
                #pragma unroll
                for (int j = 0; j < 8; ++j) vv[j] += w2[j];
            }
            #pragma unroll
            for (int j = 0; j < 8; ++j)
                Bs[k][n + j] = (IM == IM_PLAIN) ? vv[j] : elu_f(vv[j]);
        } else { // IM_PIXMAJOR: in0 is (B, HW, 128)
            #pragma unroll
            for (int half = 0; half < 2; ++half) {
                const int n = (tid >> 3) + half * 32;
                const int k = (tid & 7) * 4;
                const float4 v4 = *(const float4*)(inb + (size_t)(p0 + n) * 128 + k0 + k);
                Bs[k][n] = v4.x; Bs[k+1][n] = v4.y; Bs[k+2][n] = v4.z; Bs[k+3][n] = v4.w;
            }
        }
        __syncthreads();
        #pragma unroll
        for (int kk = 0; kk < 32; ++kk) {
            const float4 a4 = *(const float4*)&As[kk][ty * 4];
            const float4 b4 = *(const float4*)&Bs[kk][tx * 4];
            const float av[4]  = {a4.x, a4.y, a4.z, a4.w};
            const float bvv[4] = {b4.x, b4.y, b4.z, b4.w};
            #pragma unroll
            for (int mi = 0; mi < 4; ++mi)
                #pragma unroll
                for (int ni = 0; ni < 4; ++ni)
                    acc[mi][ni] = fmaf(av[mi], bvv[ni], acc[mi][ni]);
        }
        __syncthreads();
    }
    #pragma unroll
    for (int mi = 0; mi < 4; ++mi) {
        const int m = m0 + ty * 4 + mi;
        if (m >= M) continue;
        const float bv = bias[m];
        if constexpr (OM == OM_QKV) {
            const float wy = Aw[(size_t)m * wstride + 128];
            const float wx = Aw[(size_t)m * wstride + 129];
            #pragma unroll
            for (int ni = 0; ni < 4; ++ni) {
                const int p = p0 + tx * 4 + ni;
                const float py = (float)(p >> 5) * 0.03125f - 0.5f;
                const float px = (float)(p & 31) * 0.03125f - 0.5f;
                const float v = acc[mi][ni] + bv + wy * py + wx * px;
                if (m < 16)      out0[((size_t)b * HW + p) * 16 + m] = v;
                else if (m < 32) out1[((size_t)b * HW + p) * 16 + (m - 16)] = v;
                else             out2[((size_t)b * HW + p) * 128 + (m - 32)] = v;
            }
        } else {
            const int p = p0 + tx * 4;
            float vv[4];
            #pragma unroll
            for (int ni = 0; ni < 4; ++ni) vv[ni] = acc[mi][ni] + bv;
            if constexpr (OM == OM_ELU) {
                #pragma unroll
                for (int ni = 0; ni < 4; ++ni) vv[ni] = elu_f(vv[ni]);
            } else if constexpr (OM == OM_ELU_RES) {
                const float4 r4 = *(const float4*)&res[((size_t)b * 128 + m) * HW + p];
                vv[0] = elu_f(vv[0]) + r4.x; vv[1] = elu_f(vv[1]) + r4.y;
                vv[2] = elu_f(vv[2]) + r4.z; vv[3] = elu_f(vv[3]) + r4.w;
            }
            float4 ov; ov.x = vv[0]; ov.y = vv[1]; ov.z = vv[2]; ov.w = vv[3];
            *(float4*)&out0[((size_t)b * M + m) * HW + p] = ov;
        }
    }
}

// out = prev + t1*sigmoid(t2); also emit Eb = bf16(elu(out)) for next conv layer.
__global__ __launch_bounds__(256)
void gate_k(const float* __restrict__ prev, const float* __restrict__ t,
            float* __restrict__ outp, unsigned short* __restrict__ Eb)
{
    const size_t i4 = ((size_t)blockIdx.x * 256 + threadIdx.x) * 4;
    const size_t b = i4 >> 17;
    const size_t r = i4 & 131071;
    const float4 pv = *(const float4*)(prev + i4);
    const float4 t1 = *(const float4*)(t + b * 262144 + r);
    const float4 t2 = *(const float4*)(t + b * 262144 + 131072 + r);
    float4 o;
    o.x = pv.x + t1.x * sig_f(t2.x);
    o.y = pv.y + t1.y * sig_f(t2.y);
    o.z = pv.z + t1.z * sig_f(t2.z);
    o.w = pv.w + t1.w * sig_f(t2.w);
    *(float4*)(outp + i4) = o;
    ushort4 e;
    e.x = f2bf(elu_f(o.x)); e.y = f2bf(elu_f(o.y));
    e.z = f2bf(elu_f(o.z)); e.w = f2bf(elu_f(o.w));
    *(ushort4*)(Eb + i4) = e;
}

__global__ __launch_bounds__(256)
void init_k(const float* __restrict__ x, unsigned short* __restrict__ Eb)
{
    const size_t i4 = ((size_t)blockIdx.x * 256 + threadIdx.x) * 4;
    const float4 xv = *(const float4*)(x + i4);
    ushort4 e;
    e.x = f2bf(elu_f(xv.x)); e.y = f2bf(elu_f(xv.y));
    e.z = f2bf(elu_f(xv.z)); e.w = f2bf(elu_f(xv.w));
    *(ushort4*)(Eb + i4) = e;
}

// ---------------------------------------------------------------------------
// Causal flash attention, fp32, LDS-staged V, single-exp wave-parallel softmax.
// q,k (B,HW,16), v,o (B,HW,128). scale=0.25. Block: 32 queries, 256 threads.
// ---------------------------------------------------------------------------
__global__ __launch_bounds__(256)
void attn_k(const float* __restrict__ q, const float* __restrict__ k,
            const float* __restrict__ v, float* __restrict__ o)
{
    __shared__ float qs[32][17];
    __shared__ float ks[64][16];
    __shared__ float ss[32][66];     // scores, then exp(p) in place
    __shared__ float vs[64][128];    // V chunk (32 KB)
    const int tid = threadIdx.x;
    const int b  = blockIdx.y;
    const int q0 = ((int)gridDim.x - 1 - (int)blockIdx.x) * 32;   // long blocks first
    for (int e = tid; e < 512; e += 256)
        qs[e >> 4][e & 15] = q[((size_t)b * HW + q0 + (e >> 4)) * 16 + (e & 15)];
    const int si = tid & 31, sj0 = tid >> 5;   // score mapping
    const int irow = tid >> 3, dg = tid & 7;   // softmax / PV mapping
    float acc[16] = {};
    float mrun = -INFINITY, lrun = 0.f;
    const int nk = q0 + 32;
    for (int j0 = 0; j0 < nk; j0 += 64) {
        __syncthreads();
        {   // stage K chunk (64x16)
            const int j = tid >> 2, d = (tid & 3) * 4;
            *(float4*)&ks[j][d] = *(const float4*)(k + ((size_t)b * HW + j0 + j) * 16 + d);
        }
        #pragma unroll
        for (int i = 0; i < 8; ++i) {   // stage V chunk (64x128), coalesced
            const int e = tid + i * 256;
            const int row = e >> 5, c4 = (e & 31) * 4;
            *(float4*)&vs[row][c4] = *(const float4*)(v + ((size_t)b * HW + j0 + row) * 128 + c4);
        }
        __syncthreads();
        // scores
        #pragma unroll
        for (int t8 = 0; t8 < 8; ++t8) {
            const int jj = sj0 * 8 + t8;
            float dot = 0.f;
            #pragma unroll
            for (int d = 0; d < 16; ++d) dot = fmaf(qs[si][d], ks[jj][d], dot);
            ss[si][jj] = ((j0 + jj) <= (q0 + si)) ? dot * 0.25f : -INFINITY;
        }
        __syncthreads();
        // online softmax: 8 lanes per row
        float mloc = -INFINITY;
        #pragma unroll
        for (int t = 0; t < 8; ++t) mloc = fmaxf(mloc, ss[irow][dg * 8 + t]);
        mloc = fmaxf(mloc, __shfl_xor(mloc, 1, 64));
        mloc = fmaxf(mloc, __shfl_xor(mloc, 2, 64));
        mloc = fmaxf(mloc, __shfl_xor(mloc, 4, 64));
        const float mc = fmaxf(mrun, mloc);
        const float corr = __expf(mrun - mc);    // first chunk: exp(-inf)=0
        lrun *= corr;
        #pragma unroll
        for (int d = 0; d < 16; ++d) acc[d] *= corr;
        float lsum = 0.f;
        #pragma unroll
        for (int t = 0; t < 8; ++t) {
            const float e = __expf(ss[irow][dg * 8 + t] - mc);   // masked -> 0
            ss[irow][dg * 8 + t] = e;
            lsum += e;
        }
        lsum += __shfl_xor(lsum, 1, 64);
        lsum += __shfl_xor(lsum, 2, 64);
        lsum += __shfl_xor(lsum, 4, 64);
        lrun += lsum;
        mrun = mc;
        __syncthreads();
        // PV from LDS
        for (int jb = 0; jb < 64; jb += 8) {
            float p8[8];
            #pragma unroll
            for (int t = 0; t < 8; ++t) p8[t] = ss[irow][jb + t];
            #pragma unroll
            for (int t = 0; t < 8; ++t) {
                const float* vr = &vs[jb + t][dg * 16];
                #pragma unroll
                for (int d4 = 0; d4 < 4; ++d4) {
                    const float4 vv = *(const float4*)(vr + d4 * 4);
                    acc[d4*4+0] = fmaf(p8[t], vv.x, acc[d4*4+0]);
                    acc[d4*4+1] = fmaf(p8[t], vv.y, acc[d4*4+1]);
                    acc[d4*4+2] = fmaf(p8[t], vv.z, acc[d4*4+2]);
                    acc[d4*4+3] = fmaf(p8[t], vv.w, acc[d4*4+3]);
                }
            }
        }
    }
    const float inv = 1.f / lrun;
    float* orow = o + ((size_t)b * HW + q0 + irow) * 128 + dg * 16;
    #pragma unroll
    for (int d4 = 0; d4 < 4; ++d4) {
        float4 ov;
        ov.x = acc[d4*4+0] * inv; ov.y = acc[d4*4+1] * inv;
        ov.z = acc[d4*4+2] * inv; ov.w = acc[d4*4+3] * inv;
        *(float4*)(orow + d4 * 4) = ov;
    }
}

extern "C" void kernel_launch(void* const* d_in, const int* in_sizes, int n_in,
                              void* d_out, int out_size, void* d_ws, size_t ws_size,
                              hipStream_t stream) {
    const float* x    = (const float*)d_in[0];
    const float* rw1  = (const float*)d_in[1];
    const float* rb1  = (const float*)d_in[2];
    const float* rw2  = (const float*)d_in[3];
    const float* rb2  = (const float*)d_in[4];
    const float* qkvw = (const float*)d_in[5];
    const float* qkvb = (const float*)d_in[6];
    const float* apw  = (const float*)d_in[7];
    const float* apb  = (const float*)d_in[8];
    const float* ocw  = (const float*)d_in[9];
    const float* ocb  = (const float*)d_in[10];
    const float* oaw  = (const float*)d_in[11];
    const float* oab  = (const float*)d_in[12];
    const float* opw  = (const float*)d_in[13];
    const float* opb  = (const float*)d_in[14];
    float* out = (float*)d_out;
    float* ws = (float*)d_ws;

    // Workspace map (floats, 16M total = 64 MiB, temporal reuse):
    // [0,4M)    A (fp32 residual state)         | later: a1
    // [4M,12M)  t (fp32 conv2 out)              | later: q,k,v then attnout@5M
    // [12M,14M) Eb bf16 (4M ushorts)            | later: o then c1 @12M..16M
    // [14M,16M) E2 bf16 (4M ushorts)
    float* A = ws;
    float* t = ws + 4194304;
    unsigned short* Eb = (unsigned short*)(ws + 12582912);
    unsigned short* E2 = (unsigned short*)(ws + 14680064);
    float* qb = ws + 4194304;
    float* kb = ws + 4718592;
    float* vb = ws + 5242880;
    float* ob = ws + 12582912;
    float* attnout = ws + 5242880;   // overwrites v after attention
    float* c1 = ws + 12582912;       // overwrites o after attn_proj
    float* a1 = ws;                  // overwrites A after c1

    dim3 blk(256);
    init_k<<<4096, blk, 0, stream>>>(x, Eb);
    for (int i = 0; i < 6; ++i) {
        const float* prev = i ? (const float*)A : x;
        conv_mfma<128, true ><<<dim3(16, 1, 32), blk, 0, stream>>>(
            Eb, rw1 + (size_t)i * 65536, rb1 + i * 128, E2);
        conv_mfma<256, false><<<dim3(16, 1, 32), blk, 0, stream>>>(
            E2, rw2 + (size_t)i * 131072, rb2 + i * 256, t);
        gate_k<<<4096, blk, 0, stream>>>(prev, t, A, Eb);
    }
    // qkv (M=160, K=128 + analytic pos-enc cols), input = A (not elu'd)
    gemm_k<IM_PLAIN, OM_QKV><<<dim3(16, 3, 32), blk, 0, stream>>>(
        qkvw, qkvb, A, nullptr, qb, kb, vb, nullptr, 160, 128, 130);
    attn_k<<<dim3(32, 32), blk, 0, stream>>>(qb, kb, vb, ob);
    gemm_k<IM_PIXMAJOR, OM_PLAIN><<<dim3(16, 2, 32), blk, 0, stream>>>(
        apw, apb, ob, nullptr, attnout, nullptr, nullptr, nullptr, 128, 128, 128);
    gemm_k<IM_ELU, OM_ELU><<<dim3(16, 2, 32), blk, 0, stream>>>(
        ocw, ocb, A, nullptr, c1, nullptr, nullptr, nullptr, 128, 128, 128);
    gemm_k<IM_ELU, OM_ELU><<<dim3(16, 2, 32), blk, 0, stream>>>(
        oaw, oab, attnout, nullptr, a1, nullptr, nullptr, nullptr, 128, 128, 128);
    gemm_k<IM_ELU_SUM, OM_ELU_RES><<<dim3(16, 2, 32), blk, 0, stream>>>(
        opw, opb, c1, a1, out, nullptr, nullptr, x, 128, 128, 128);
}

// Round 3
// 558.981 us; speedup vs baseline: 4.1592x; 1.8062x over previous
//
#include <hip/hip_runtime.h>
#include <math.h>

#define HW 1024
typedef unsigned short u16;
typedef __attribute__((ext_vector_type(8))) short short8v;   // 8 bf16
typedef __attribute__((ext_vector_type(4))) float f32x4;
typedef __attribute__((ext_vector_type(16))) float f32x16;

__device__ __forceinline__ float elu_f(float x){ return x>0.f? x : (__expf(x)-1.f); }
__device__ __forceinline__ float sig_f(float x){ return 1.f/(1.f+__expf(-x)); }
__device__ __forceinline__ u16 f2bf(float f){ unsigned u=__float_as_uint(f); return (u16)((u + 0x7fffu + ((u>>16)&1u))>>16); }
__device__ __forceinline__ float bf2f(u16 h){ return __uint_as_float(((unsigned)h)<<16); }

// ---------------------------------------------------------------------------
// Weight converts (one-time): 2x2 convs get tap-major K reorder (k' = tap*128+c)
// ---------------------------------------------------------------------------
__global__ __launch_bounds__(256)
void wc2_k(const float* __restrict__ rw, u16* __restrict__ wb, int total)
{
    int i = blockIdx.x*256 + threadIdx.x;
    if (i >= total) return;
    int kp = i & 511, row = i >> 9;
    int tap = kp >> 7, c = kp & 127;
    wb[i] = f2bf(rw[(size_t)row*512 + c*4 + tap]);
}
__global__ __launch_bounds__(256)
void wc1_k(const float* __restrict__ w0, const float* __restrict__ w1,
           const float* __restrict__ w2, const float* __restrict__ w3, u16* __restrict__ wb)
{
    int i = blockIdx.x*256 + threadIdx.x;   // 0..65535
    const float* src = (i<16384)? w0 : (i<32768)? w1 : (i<49152)? w2 : w3;
    wb[i] = f2bf(src[i & 16383]);
}

// ---------------------------------------------------------------------------
// init: x (B,128,HW) f32 -> A (B,HW,128) f32 pixel-major + Eb bf16(elu(x))
// ---------------------------------------------------------------------------
__global__ __launch_bounds__(256)
void init_k(const float* __restrict__ x, float* __restrict__ A, u16* __restrict__ Eb)
{
    __shared__ float t[32][132];
    const int b = blockIdx.y, p0 = blockIdx.x*32;
    const int tid = threadIdx.x;
    const int cr = tid >> 3, p4 = (tid & 7)*4;
    #pragma unroll
    for (int cc = 0; cc < 128; cc += 32) {
        const float4 v = *(const float4*)(x + ((size_t)b*128 + cc + cr)*HW + p0 + p4);
        t[p4+0][cc+cr]=v.x; t[p4+1][cc+cr]=v.y; t[p4+2][cc+cr]=v.z; t[p4+3][cc+cr]=v.w;
    }
    __syncthreads();
    const int pr = tid >> 3, c4 = (tid & 7)*4;
    #pragma unroll
    for (int cc = 0; cc < 128; cc += 32) {
        const int c = cc + c4;
        float4 v; v.x=t[pr][c]; v.y=t[pr][c+1]; v.z=t[pr][c+2]; v.w=t[pr][c+3];
        *(float4*)(A + ((size_t)b*HW + p0 + pr)*128 + c) = v;
        ushort4 e;
        e.x=f2bf(elu_f(v.x)); e.y=f2bf(elu_f(v.y)); e.z=f2bf(elu_f(v.z)); e.w=f2bf(elu_f(v.w));
        *(ushort4*)(Eb + ((size_t)b*HW + p0 + pr)*128 + c) = e;
    }
}

// ---------------------------------------------------------------------------
// Flat MFMA conv (2x2 im2col tap-major or 1x1). LDS-free: every fragment is a
// contiguous 16B global load. Block = 64px x NOUT ch, 4 waves (2ch x 2px).
// EPI 0: out = bf16(elu(acc+bias))            (NOUT=128)
// EPI 1: gate fused (NOUT=256): o = A + t1*sig(t2); A=o (f32); out0=bf16(elu(o))
// EPI 2: s = elu(acc+bias) + bf16(aux); out0 = bf16(elu(s))   (NOUT=128)
// ---------------------------------------------------------------------------
template<int NOUT, int TAPS, int EPI>
__global__ __launch_bounds__(256)
void convf(const u16* __restrict__ Wb, const float* __restrict__ bias,
           const u16* __restrict__ Ein, u16* __restrict__ out0,
           float* __restrict__ Aio, const u16* __restrict__ aux)
{
    constexpr int K  = TAPS*128;
    constexpr int NF = NOUT/32;
    const int tid = threadIdx.x;
    const int b = blockIdx.z, p0 = blockIdx.x*64;
    const int wave = tid>>6, lane = tid&63;
    const int px0 = (wave&1)*32, ch0 = (wave>>1)*64;
    const int lr = lane&15, lg = lane>>4;

    int cfr[NF];
    #pragma unroll
    for (int mf=0; mf<NF; ++mf)
        cfr[mf] = (EPI==1) ? ((mf<4)? ch0+mf*16 : 128+ch0+(mf-4)*16) : ch0+mf*16;
    const u16* wp[NF];
    #pragma unroll
    for (int mf=0; mf<NF; ++mf) wp[mf] = Wb + (size_t)(cfr[mf]+lr)*K + lg*8;
    int pp[2];
    #pragma unroll
    for (int nf=0; nf<2; ++nf) pp[nf] = p0 + px0 + nf*16 + lr;
    const u16* eb = Ein + (size_t)b*HW*128;
    unsigned okm[2];
    #pragma unroll
    for (int nf=0; nf<2; ++nf) {
        if (TAPS==1) okm[nf] = 0xF;
        else {
            int py = pp[nf]>>5, px = pp[nf]&31;
            okm[nf] = 8u | ((py>0&&px>0)?1u:0u) | ((py>0)?2u:0u) | ((px>0)?4u:0u);
        }
    }
    f32x4 acc[NF][2] = {};
    const int OFF[4] = {-33,-32,-1,0};
    const short8v zv = {};
    #pragma unroll 4
    for (int k0 = 0; k0 < K; k0 += 32) {
        const int tap = k0>>7, c0 = k0&127;
        short8v bv[2];
        #pragma unroll
        for (int nf=0; nf<2; ++nf) {
            const bool ok = (okm[nf]>>tap)&1;
            const int prd = (TAPS==4 && ok) ? OFF[tap] : 0;
            const short8v ld = *(const short8v*)(eb + (size_t)(pp[nf]+prd)*128 + c0 + lg*8);
            bv[nf] = ok ? ld : zv;
        }
        #pragma unroll
        for (int mf=0; mf<NF; ++mf) {
            const short8v av = *(const short8v*)(wp[mf] + k0);
            acc[mf][0] = __builtin_amdgcn_mfma_f32_16x16x32_bf16(av, bv[0], acc[mf][0],0,0,0);
            acc[mf][1] = __builtin_amdgcn_mfma_f32_16x16x32_bf16(av, bv[1], acc[mf][1],0,0,0);
        }
    }
    // epilogue: D lane: col(px) = l&15 (== pp[nf]), rows(ch) = cfr[mf] + 4*lg + r
    if constexpr (EPI == 1) {
        #pragma unroll
        for (int mf=0; mf<4; ++mf) {
            const int c1b = ch0 + mf*16 + lg*4;
            const float4 b1 = *(const float4*)(bias + c1b);
            const float4 b2 = *(const float4*)(bias + 128 + c1b);
            #pragma unroll
            for (int nf=0; nf<2; ++nf) {
                const int px = pp[nf];
                float* ap = Aio + ((size_t)b*HW + px)*128 + c1b;
                const float4 pv = *(const float4*)ap;
                float o0 = pv.x + (acc[mf][nf][0]+b1.x)*sig_f(acc[mf+4][nf][0]+b2.x);
                float o1 = pv.y + (acc[mf][nf][1]+b1.y)*sig_f(acc[mf+4][nf][1]+b2.y);
                float o2 = pv.z + (acc[mf][nf][2]+b1.z)*sig_f(acc[mf+4][nf][2]+b2.z);
                float o3 = pv.w + (acc[mf][nf][3]+b1.w)*sig_f(acc[mf+4][nf][3]+b2.w);
                float4 ov; ov.x=o0; ov.y=o1; ov.z=o2; ov.w=o3;
                *(float4*)ap = ov;
                ushort4 e;
                e.x=f2bf(elu_f(o0)); e.y=f2bf(elu_f(o1)); e.z=f2bf(elu_f(o2)); e.w=f2bf(elu_f(o3));
                *(ushort4*)(out0 + ((size_t)b*HW + px)*128 + c1b) = e;
            }
        }
    } else {
        #pragma unroll
        for (int mf=0; mf<NF; ++mf) {
            const int cb = cfr[mf] + lg*4;
            const float4 bb = *(const float4*)(bias + cb);
            #pragma unroll
            for (int nf=0; nf<2; ++nf) {
                const int px = pp[nf];
                float v0 = acc[mf][nf][0]+bb.x, v1 = acc[mf][nf][1]+bb.y;
                float v2 = acc[mf][nf][2]+bb.z, v3 = acc[mf][nf][3]+bb.w;
                ushort4 e;
                if constexpr (EPI == 2) {
                    const ushort4 c4 = *(const ushort4*)(aux + ((size_t)b*HW + px)*128 + cb);
                    e.x = f2bf(elu_f(elu_f(v0) + bf2f(c4.x)));
                    e.y = f2bf(elu_f(elu_f(v1) + bf2f(c4.y)));
                    e.z = f2bf(elu_f(elu_f(v2) + bf2f(c4.z)));
                    e.w = f2bf(elu_f(elu_f(v3) + bf2f(c4.w)));
                } else {
                    e.x=f2bf(elu_f(v0)); e.y=f2bf(elu_f(v1));
                    e.z=f2bf(elu_f(v2)); e.w=f2bf(elu_f(v3));
                }
                *(ushort4*)(out0 + ((size_t)b*HW + px)*128 + cb) = e;
            }
        }
    }
}

// ---------------------------------------------------------------------------
// Final 1x1 conv, channel-major f32 out: y = elu(W*Es + b) + x. D rows = pixels.
// ---------------------------------------------------------------------------
__global__ __launch_bounds__(256)
void convcm(const u16* __restrict__ Wb, const float* __restrict__ bias,
            const u16* __restrict__ Es, const float* __restrict__ x, float* __restrict__ out)
{
    const int tid = threadIdx.x, b = blockIdx.z, p0 = blockIdx.x*64;
    const int wave = tid>>6, lane = tid&63;
    const int px0 = (wave&1)*32, oc0 = (wave>>1)*64;
    const int lr = lane&15, lg = lane>>4;
    f32x4 acc[2][4] = {};
    const u16* ep[2];
    #pragma unroll
    for (int mi=0; mi<2; ++mi) ep[mi] = Es + ((size_t)b*HW + p0+px0+mi*16+lr)*128 + lg*8;
    const u16* wq[4];
    #pragma unroll
    for (int ni=0; ni<4; ++ni) wq[ni] = Wb + (size_t)(oc0+ni*16+lr)*128 + lg*8;
    #pragma unroll
    for (int k0=0; k0<128; k0+=32) {
        short8v am[2];
        #pragma unroll
        for (int mi=0; mi<2; ++mi) am[mi] = *(const short8v*)(ep[mi]+k0);
        #pragma unroll
        for (int ni=0; ni<4; ++ni) {
            const short8v bw = *(const short8v*)(wq[ni]+k0);
            acc[0][ni] = __builtin_amdgcn_mfma_f32_16x16x32_bf16(am[0], bw, acc[0][ni],0,0,0);
            acc[1][ni] = __builtin_amdgcn_mfma_f32_16x16x32_bf16(am[1], bw, acc[1][ni],0,0,0);
        }
    }
    #pragma unroll
    for (int mi=0; mi<2; ++mi) {
        const int pxb = p0 + px0 + mi*16 + lg*4;
        #pragma unroll
        for (int ni=0; ni<4; ++ni) {
            const int oc = oc0 + ni*16 + lr;
            const float bv = bias[oc];
            const float4 xr = *(const float4*)(x + ((size_t)b*128 + oc)*HW + pxb);
            float4 o;
            o.x = elu_f(acc[mi][ni][0]+bv) + xr.x;
            o.y = elu_f(acc[mi][ni][1]+bv) + xr.y;
            o.z = elu_f(acc[mi][ni][2]+bv) + xr.z;
            o.w = elu_f(acc[mi][ni][3]+bv) + xr.w;
            *(float4*)(out + ((size_t)b*128 + oc)*HW + pxb) = o;
        }
    }
}

// ---------------------------------------------------------------------------
// qkv: fp32 GEMM (M=160,K=128) + pos-enc cols; q,k -> bf16 (B,HW,16) (0.25 in q),
// v -> bf16 V^T (B,128,HW).
// ---------------------------------------------------------------------------
__global__ __launch_bounds__(256)
void qkv_k(const float* __restrict__ W, const float* __restrict__ bias,
           const float* __restrict__ A, u16* __restrict__ qo, u16* __restrict__ ko,
           u16* __restrict__ vo)
{
    __shared__ float As[32][68];
    __shared__ float Bs[32][68];
    const int tid = threadIdx.x, b = blockIdx.z;
    const int p0 = blockIdx.x*64, m0 = blockIdx.y*64;
    const int tx = tid&15, ty = tid>>4;
    float acc[4][4] = {};
    const float* Ab = A + (size_t)b*HW*128;
    for (int k0=0; k0<128; k0+=32) {
        {
            const int m = tid>>2, kb = (tid&3)*8;
            const bool mok = (m0+m) < 160;
            const float* wr = W + (size_t)(m0+m)*130 + k0 + kb;
            #pragma unroll
            for (int j=0;j<8;++j) As[kb+j][m] = mok ? wr[j] : 0.f;
        }
        #pragma unroll
        for (int half=0; half<2; ++half) {
            const int n = (tid>>3) + half*32, kk = (tid&7)*4;
            const float4 v4 = *(const float4*)(Ab + (size_t)(p0+n)*128 + k0+kk);
            Bs[kk][n]=v4.x; Bs[kk+1][n]=v4.y; Bs[kk+2][n]=v4.z; Bs[kk+3][n]=v4.w;
        }
        __syncthreads();
        #pragma unroll
        for (int kk=0; kk<32; ++kk) {
            const float4 a4 = *(const float4*)&As[kk][ty*4];
            const float4 b4 = *(const float4*)&Bs[kk][tx*4];
            const float av[4]={a4.x,a4.y,a4.z,a4.w}, bv[4]={b4.x,b4.y,b4.z,b4.w};
            #pragma unroll
            for (int mi=0;mi<4;++mi)
                #pragma unroll
                for (int ni=0;ni<4;++ni)
                    acc[mi][ni] = fmaf(av[mi], bv[ni], acc[mi][ni]);
        }
        __syncthreads();
    }
    #pragma unroll
    for (int mi=0;mi<4;++mi) {
        const int m = m0 + ty*4 + mi;
        if (m >= 160) continue;
        const float bv = bias[m];
        const float wy = W[(size_t)m*130 + 128], wx = W[(size_t)m*130 + 129];
        #pragma unroll
        for (int ni=0;ni<4;++ni) {
            const int p = p0 + tx*4 + ni;
            const float py = (float)(p>>5)*0.03125f - 0.5f;
            const float px = (float)(p&31)*0.03125f - 0.5f;
            const float v = acc[mi][ni] + bv + wy*py + wx*px;
            if (m < 16)       qo[((size_t)b*HW + p)*16 + m]        = f2bf(0.25f*v);
            else if (m < 32)  ko[((size_t)b*HW + p)*16 + (m-16)]   = f2bf(v);
            else              vo[((size_t)b*128 + (m-32))*HW + p]  = f2bf(v);
        }
    }
}

// ---------------------------------------------------------------------------
// MFMA causal attention. One wave per 32-query tile. 32x32x16 bf16 MFMAs.
// S^T = mfma(K, Q): lane owns q-col = lane&31; softmax in-lane + shfl_xor(32).
// PV: O^T = mfma(V^T, P^T) with P^T built via bf16 pack + half-swap.
// q,k: (B,HW,16) bf16 (0.25 folded into q); v: V^T (B,128,HW) bf16;
// o: (B,HW,128) bf16.
// ---------------------------------------------------------------------------
__global__ __launch_bounds__(64)
void attn_mfma(const u16* __restrict__ qb, const u16* __restrict__ kb,
               const u16* __restrict__ vb, u16* __restrict__ ob)
{
    const int lane = threadIdx.x;
    const int bid  = blockIdx.x;            // 0..1023
    const int qt   = 31 - (bid >> 5);       // long tiles first
    const int b    = bid & 31;
    const int q0   = qt * 32;
    const int lq = lane & 31, hf = lane >> 5;

    const short8v Qf = *(const short8v*)(qb + ((size_t)b*HW + q0 + lq)*16 + hf*8);
    f32x16 acc[4] = {{},{},{},{}};
    float mrun = -1e30f, lrun = 0.f;

    unsigned diagm = 0;
    #pragma unroll
    for (int r=0; r<16; ++r) {
        const int row = (r&3) + 8*(r>>2) + 4*hf;
        diagm |= (row <= lq) ? (1u<<r) : 0u;
    }
    const f32x16 zc = {};
    for (int c = 0; c <= qt; ++c) {
        const int kv0 = c*32;
        const short8v Kf = *(const short8v*)(kb + ((size_t)b*HW + kv0 + lq)*16 + hf*8);
        f32x16 st = __builtin_amdgcn_mfma_f32_32x32x16_bf16(Kf, Qf, zc, 0,0,0);
        if (c == qt) {
            #pragma unroll
            for (int r=0; r<16; ++r)
                st[r] = ((diagm>>r)&1) ? st[r] : -1e30f;
        }
        float mc = st[0];
        #pragma unroll
        for (int r=1; r<16; ++r) mc = fmaxf(mc, st[r]);
        mc = fmaxf(mc, __shfl_xor(mc, 32));
        if (!__all(mc <= mrun)) {
            const float mnew = fmaxf(mrun, mc);
            const float corr = __expf(mrun - mnew);
            lrun *= corr;
            #pragma unroll
            for (int f=0; f<4; ++f)
                #pragma unroll
                for (int r=0; r<16; ++r) acc[f][r] *= corr;
            mrun = mnew;
        }
        float ps[16]; float lsum = 0.f;
        #pragma unroll
        for (int r=0; r<16; ++r) { ps[r] = __expf(st[r] - mrun); lsum += ps[r]; }
        lrun += lsum + __shfl_xor(lsum, 32);
        // pack P pairs to bf16 and swap halves
        unsigned pk[8], sw[8];
        #pragma unroll
        for (int i=0; i<8; ++i)
            pk[i] = (unsigned)f2bf(ps[2*i]) | ((unsigned)f2bf(ps[2*i+1])<<16);
        #pragma unroll
        for (int i=0; i<8; ++i) sw[i] = __shfl_xor(pk[i], 32);
        union { unsigned u[4]; short8v v; } B1, B2;
        B1.u[0] = hf ? sw[2] : pk[0];  B1.u[1] = hf ? sw[3] : pk[1];
        B1.u[2] = hf ? pk[2] : sw[0];  B1.u[3] = hf ? pk[3] : sw[1];
        B2.u[0] = hf ? sw[6] : pk[4];  B2.u[1] = hf ? sw[7] : pk[5];
        B2.u[2] = hf ? pk[6] : sw[4];  B2.u[3] = hf ? pk[7] : sw[5];
        #pragma unroll
        for (int f=0; f<4; ++f) {
            const u16* vr = vb + ((size_t)b*128 + f*32 + lq)*HW + kv0 + hf*8;
            const short8v A1 = *(const short8v*)(vr);
            const short8v A2 = *(const short8v*)(vr + 16);
            acc[f] = __builtin_amdgcn_mfma_f32_32x32x16_bf16(A1, B1.v, acc[f], 0,0,0);
            acc[f] = __builtin_amdgcn_mfma_f32_32x32x16_bf16(A2, B2.v, acc[f], 0,0,0);
        }
    }
    const float inv = 1.f / lrun;
    u16* orow = ob + ((size_t)b*HW + q0 + lq)*128;
    #pragma unroll
    for (int f=0; f<4; ++f) {
        #pragma unroll
        for (int g=0; g<4; ++g) {
            const int d0 = f*32 + 8*g + 4*hf;
            ushort4 o4;
            o4.x = f2bf(acc[f][g*4+0]*inv);
            o4.y = f2bf(acc[f][g*4+1]*inv);
            o4.z = f2bf(acc[f][g*4+2]*inv);
            o4.w = f2bf(acc[f][g*4+3]*inv);
            *(ushort4*)(orow + d0) = o4;
        }
    }
}

extern "C" void kernel_launch(void* const* d_in, const int* in_sizes, int n_in,
                              void* d_out, int out_size, void* d_ws, size_t ws_size,
                              hipStream_t stream) {
    const float* x    = (const float*)d_in[0];
    const float* rw1  = (const float*)d_in[1];
    const float* rb1  = (const float*)d_in[2];
    const float* rw2  = (const float*)d_in[3];
    const float* rb2  = (const float*)d_in[4];
    const float* qkvw = (const float*)d_in[5];
    const float* qkvb = (const float*)d_in[6];
    const float* apw  = (const float*)d_in[7];
    const float* apb  = (const float*)d_in[8];
    const float* ocw  = (const float*)d_in[9];
    const float* ocb  = (const float*)d_in[10];
    const float* oaw  = (const float*)d_in[11];
    const float* oab  = (const float*)d_in[12];
    const float* opw  = (const float*)d_in[13];
    const float* opb  = (const float*)d_in[14];
    float* out = (float*)d_out;
    float* ws = (float*)d_ws;

    // Workspace (float offsets, 64 MiB total):
    float* A  = ws;                                  // [0, 4M)   (B,HW,128) f32
    u16* Eb   = (u16*)(ws + 4194304);                // [4M, 6M)  bf16(elu(state))
    u16* E2   = (u16*)(ws + 6291456);                // [6M, 8M)  conv1 out / c1'
    u16* qb   = (u16*)(ws + 8388608);                // [8M, 8.25M)
    u16* kb   = (u16*)(ws + 8650752);                // [8.25M, 8.5M)
    u16* vb   = (u16*)(ws + 8912896);                // [8.5M, 10.5M)  V^T
    u16* ob   = (u16*)(ws + 11010048);               // [10.5M, 12.5M)
    u16* Ea   = (u16*)(ws + 13107200);               // [12.5M, 14.5M)
    u16* Es   = (u16*)(ws + 8388608);                // reuse qkv region
    u16* w1b  = (u16*)(ws + 15204352);               // 6*128*512
    u16* w2b  = (u16*)(ws + 15400960);               // 6*256*512
    u16* wh   = (u16*)(ws + 15794176);               // 4*128*128 (ap, oc, oa, op)
    u16* c1p  = E2;

    dim3 blk(256);
    wc2_k<<<1536, blk, 0, stream>>>(rw1, w1b, 6*128*512);
    wc2_k<<<3072, blk, 0, stream>>>(rw2, w2b, 6*256*512);
    wc1_k<<<256,  blk, 0, stream>>>(apw, ocw, oaw, opw, wh);
    init_k<<<dim3(32, 32), blk, 0, stream>>>(x, A, Eb);
    for (int i = 0; i < 6; ++i) {
        convf<128,4,0><<<dim3(16,1,32), blk, 0, stream>>>(
            w1b + (size_t)i*65536, rb1 + i*128, Eb, E2, nullptr, nullptr);
        convf<256,4,1><<<dim3(16,1,32), blk, 0, stream>>>(
            w2b + (size_t)i*131072, rb2 + i*256, E2, Eb, A, nullptr);
    }
    qkv_k<<<dim3(16,3,32), blk, 0, stream>>>(qkvw, qkvb, A, qb, kb, vb);
    attn_mfma<<<1024, dim3(64), 0, stream>>>(qb, kb, vb, ob);
    // attn_proj -> Ea = bf16(elu(attn_out))
    convf<128,1,0><<<dim3(16,1,32), blk, 0, stream>>>(wh, apb, ob, Ea, nullptr, nullptr);
    // out_conv -> c1' = bf16(elu(c1))
    convf<128,1,0><<<dim3(16,1,32), blk, 0, stream>>>(wh + 16384, ocb, Eb, c1p, nullptr, nullptr);
    // out_attn + add c1 -> Es = bf16(elu(c1+a1))
    convf<128,1,2><<<dim3(16,1,32), blk, 0, stream>>>(wh + 32768, oab, Ea, Es, nullptr, c1p);
    // out_proj -> y = elu(.)+x, channel-major f32
    convcm<<<dim3(16,1,32), blk, 0, stream>>>(wh + 49152, opb, Es, x, out);
}